// Round 4
// baseline (597.154 us; speedup 1.0000x reference)
//
#include <hip/hip_runtime.h>
#include <hip/hip_bf16.h>
#include <math.h>

#define B_   2
#define S_   2048
#define H_   2048
#define NH_  32
#define HD_  64

typedef __bf16 bf16_t;
typedef bf16_t bf16x8 __attribute__((ext_vector_type(8)));
typedef float  f32x4  __attribute__((ext_vector_type(4)));

__device__ __forceinline__ float bf2f(unsigned short u) {
  unsigned int x = ((unsigned int)u) << 16;
  return __builtin_bit_cast(float, x);
}
__device__ __forceinline__ unsigned short f2bf(float f) {
  unsigned int u = __builtin_bit_cast(unsigned int, f);
  u += 0x7FFFu + ((u >> 16) & 1u);
  return (unsigned short)(u >> 16);
}

__device__ __forceinline__ void gload16(const void* g, void* l) {
  __builtin_amdgcn_global_load_lds((const __attribute__((address_space(1))) void*)g,
                                   (__attribute__((address_space(3))) void*)l, 16, 0, 0);
}

// ---------------------------------------------------------------- cast fp32 -> bf16
__global__ void cast_kernel(const float* __restrict__ in, unsigned short* __restrict__ out, int n4) {
  int stride = gridDim.x * blockDim.x;
  for (int i = blockIdx.x * blockDim.x + threadIdx.x; i < n4; i += stride) {
    float4 v = reinterpret_cast<const float4*>(in)[i];
    ushort4 o;
    o.x = f2bf(v.x); o.y = f2bf(v.y); o.z = f2bf(v.z); o.w = f2bf(v.w);
    reinterpret_cast<ushort4*>(out)[i] = o;
  }
}

// ---------------------------------------------------------------- GEMM (A[M][K] x Bt[N][K])
template<int EPI>
__global__ __launch_bounds__(256) void gemm_bt(
    const unsigned short* __restrict__ A, const unsigned short* __restrict__ Bt,
    float* __restrict__ outF,
    unsigned short* __restrict__ qb, unsigned short* __restrict__ kb, unsigned short* __restrict__ vt,
    int M, int N, int K)
{
  __shared__ unsigned short As[128 * 64];
  __shared__ unsigned short Bs[128 * 64];
  const int tid  = threadIdx.x;
  const int lane = tid & 63;
  const int wave = tid >> 6;
  const int lo = lane & 15, hi = lane >> 4;
  const int wr = wave >> 1, wc = wave & 1;
  const int m0 = blockIdx.x * 128;
  const int n0 = blockIdx.y * 128;

  const unsigned short* asrc[4];
  const unsigned short* bsrc[4];
  unsigned short* adst[4];
  unsigned short* bdst[4];
#pragma unroll
  for (int i = 0; i < 4; ++i) {
    int idx = i * 256 + tid;
    int r  = idx >> 3;
    int cb = (idx & 7) * 16;
    int cs = cb ^ ((r & 7) << 4);
    asrc[i] = A  + (size_t)(m0 + r) * K + (cs >> 1);
    bsrc[i] = Bt + (size_t)(n0 + r) * K + (cs >> 1);
    adst[i] = &As[idx * 8];
    bdst[i] = &Bs[idx * 8];
  }

  f32x4 zero = {0.f, 0.f, 0.f, 0.f};
  f32x4 acc[4][4];
#pragma unroll
  for (int i = 0; i < 4; ++i)
#pragma unroll
    for (int j = 0; j < 4; ++j) acc[i][j] = zero;

  for (int k0 = 0; k0 < K; k0 += 64) {
    __syncthreads();
#pragma unroll
    for (int i = 0; i < 4; ++i) gload16(asrc[i] + k0, adst[i]);
#pragma unroll
    for (int i = 0; i < 4; ++i) gload16(bsrc[i] + k0, bdst[i]);
    __syncthreads();
#pragma unroll
    for (int kk = 0; kk < 2; ++kk) {
      bf16x8 af[4], bfm[4];
#pragma unroll
      for (int i = 0; i < 4; ++i) {
        int ra = wr * 64 + i * 16 + lo;
        af[i] = *reinterpret_cast<const bf16x8*>(
            (const char*)As + ra * 128 + ((kk * 64 + hi * 16) ^ ((ra & 7) << 4)));
        int rb = wc * 64 + i * 16 + lo;
        bfm[i] = *reinterpret_cast<const bf16x8*>(
            (const char*)Bs + rb * 128 + ((kk * 64 + hi * 16) ^ ((rb & 7) << 4)));
      }
#pragma unroll
      for (int i = 0; i < 4; ++i)
#pragma unroll
        for (int j = 0; j < 4; ++j)
          acc[i][j] = __builtin_amdgcn_mfma_f32_16x16x32_bf16(af[i], bfm[j], acc[i][j], 0, 0, 0);
    }
  }

#pragma unroll
  for (int i = 0; i < 4; ++i) {
#pragma unroll
    for (int j = 0; j < 4; ++j) {
#pragma unroll
      for (int r = 0; r < 4; ++r) {
        int row = m0 + wr * 64 + i * 16 + hi * 4 + r;
        int col = n0 + wc * 64 + j * 16 + lo;
        float v = acc[i][j][r];
        if (EPI == 0) {
          int sec = col >> 11;
          int hh  = (col >> 6) & 31;
          int d   = col & 63;
          int b   = row >> 11;
          int s   = row & 2047;
          unsigned short bv = f2bf(v);
          if (sec == 0)      qb[((size_t)(b * NH_ + hh) * S_ + s) * HD_ + d] = bv;
          else if (sec == 1) kb[((size_t)(b * NH_ + hh) * S_ + s) * HD_ + d] = bv;
          else               vt[((size_t)(b * NH_ + hh) * HD_ + d) * S_ + s] = bv;
        } else {
          outF[(size_t)row * N + col] = v;
        }
      }
    }
  }
}

// ---------------------------------------------------------------- RoPE (in-place on bf16 Q/K)
__global__ void rope_kernel(unsigned short* __restrict__ qb, unsigned short* __restrict__ kb,
                            const int* __restrict__ pos) {
  int idx = blockIdx.x * blockDim.x + threadIdx.x;
  if (idx >= B_ * NH_ * S_) return;
  int s  = idx & (S_ - 1);
  int bh = idx >> 11;
  int b  = bh >> 5;
  float p = (float)pos[b * S_ + s];
  const float invf[8] = {1.0f, 0.31622776601683794f, 0.1f, 0.031622776601683791f,
                         0.01f, 0.0031622776601683794f, 0.001f, 0.00031622776601683794f};
  unsigned short* q = qb + (size_t)idx * HD_;
  unsigned short* k = kb + (size_t)idx * HD_;
#pragma unroll
  for (int i = 0; i < 8; ++i) {
    float ang = p * invf[i];
    float sn, c;
    sincosf(ang, &sn, &c);
    float q1 = bf2f(q[i]), q2 = bf2f(q[i + 8]);
    q[i]     = f2bf(q1 * c - q2 * sn);
    q[i + 8] = f2bf(q2 * c + q1 * sn);
    float k1 = bf2f(k[i]), k2 = bf2f(k[i + 8]);
    k[i]     = f2bf(k1 * c - k2 * sn);
    k[i + 8] = f2bf(k2 * c + k1 * sn);
  }
}

// ---------------------------------------------------------------- causal flash attention
// 256 q-rows/block, 8 waves x 32 rows. K/V triple-buffered (2-deep prefetch) via
// global_load_lds (pre-swizzled source, XOR bank swizzle), counted vmcnt.
// Softmax in exp2 domain (log2e folded into Q pre-scale).
__global__ __launch_bounds__(512, 3) void attn_fwd(
    const unsigned short* __restrict__ qb, const unsigned short* __restrict__ kb,
    const unsigned short* __restrict__ vt, unsigned short* __restrict__ ob)
{
  __shared__ unsigned short Ks[3][64 * 64];
  __shared__ unsigned short Vs[3][64 * 64];
  __shared__ unsigned short Ps[8][32 * 64];
  const int qt   = (int)gridDim.x - 1 - (int)blockIdx.x;  // heavy tiles dispatch first
  const int bh   = blockIdx.y;
  const int tid  = threadIdx.x;
  const int lane = tid & 63;
  const int wave = tid >> 6;
  const int lo = lane & 15, hi = lane >> 4;
  const int b = bh >> 5, h = bh & 31;
  const unsigned short* Qg = qb + (size_t)bh * S_ * HD_;
  const unsigned short* Kg = kb + (size_t)bh * S_ * HD_;
  const unsigned short* Vg = vt + (size_t)bh * HD_ * S_;

  const int qrow0 = qt * 256 + wave * 32;

  // Q fragments, pre-scaled by (1/8)*log2(e) so scores are in log2 domain
  const float qscale = 0.125f * 1.4426950408889634f;
  bf16x8 aq[2][2];
#pragma unroll
  for (int rf = 0; rf < 2; ++rf)
#pragma unroll
    for (int kk = 0; kk < 2; ++kk) {
      bf16x8 t = *reinterpret_cast<const bf16x8*>(
          Qg + (size_t)(qrow0 + rf * 16 + lo) * HD_ + kk * 32 + hi * 8);
#pragma unroll
      for (int e = 0; e < 8; ++e) aq[rf][kk][e] = (bf16_t)((float)t[e] * qscale);
    }

  f32x4 zero = {0.f, 0.f, 0.f, 0.f};
  float m_s[2][4], l_s[2][4];
  f32x4 o_acc[2][4];
#pragma unroll
  for (int rf = 0; rf < 2; ++rf)
#pragma unroll
    for (int r = 0; r < 4; ++r) { m_s[rf][r] = -1e30f; l_s[rf][r] = 0.f; }
#pragma unroll
  for (int rf = 0; rf < 2; ++rf)
#pragma unroll
    for (int dt = 0; dt < 4; ++dt) o_acc[rf][dt] = zero;

  // 512 threads stage one 64x64 K tile + one 64x64 V tile (1 gload each)
  auto stage = [&](int kt, int buf) {
    int r  = tid >> 3;
    int cs = ((tid & 7) * 16) ^ ((r & 7) << 4);
    gload16(Kg + (size_t)(kt * 64 + r) * HD_ + (cs >> 1), &Ks[buf][tid * 8]);
    gload16(Vg + (size_t)r * S_ + kt * 64 + (cs >> 1), &Vs[buf][tid * 8]);
  };

  const int nkt = 4 * qt + 4;
  stage(0, 0);
  stage(1, 1);

  for (int kt = 0; kt < nkt; ++kt) {
    const int cur = kt % 3;
    if (kt + 2 < nkt) {
      stage(kt + 2, (kt + 2) % 3);
      asm volatile("s_waitcnt vmcnt(4)" ::: "memory");
    } else if (kt + 2 == nkt) {
      asm volatile("s_waitcnt vmcnt(2)" ::: "memory");
    } else {
      asm volatile("s_waitcnt vmcnt(0)" ::: "memory");
    }
    __builtin_amdgcn_s_barrier();
    __builtin_amdgcn_sched_barrier(0);

    // wave-uniform skip: this wave's rows are all below this K tile
    if (kt * 64 <= qrow0 + 31) {
      // ---- QK^T: scores (log2 domain) for 32 rows x 64 cols per wave
      bf16x8 bk[4][2];
#pragma unroll
      for (int ct = 0; ct < 4; ++ct)
#pragma unroll
        for (int kk = 0; kk < 2; ++kk) {
          int row = ct * 16 + lo;
          bk[ct][kk] = *reinterpret_cast<const bf16x8*>(
              (const char*)&Ks[cur][0] + row * 128 + ((kk * 64 + hi * 16) ^ ((row & 7) << 4)));
        }
      f32x4 sc[2][4];
      __builtin_amdgcn_s_setprio(1);
#pragma unroll
      for (int rf = 0; rf < 2; ++rf)
#pragma unroll
        for (int ct = 0; ct < 4; ++ct) {
          f32x4 a = zero;
          a = __builtin_amdgcn_mfma_f32_16x16x32_bf16(aq[rf][0], bk[ct][0], a, 0, 0, 0);
          a = __builtin_amdgcn_mfma_f32_16x16x32_bf16(aq[rf][1], bk[ct][1], a, 0, 0, 0);
          sc[rf][ct] = a;
        }
      __builtin_amdgcn_s_setprio(0);

      // ---- causal mask (only for the diagonal tile of this wave)
      if (kt * 64 + 63 > qrow0) {
#pragma unroll
        for (int rf = 0; rf < 2; ++rf)
#pragma unroll
          for (int ct = 0; ct < 4; ++ct)
#pragma unroll
            for (int rr = 0; rr < 4; ++rr) {
              int qrow = qrow0 + rf * 16 + hi * 4 + rr;
              int kcol = kt * 64 + ct * 16 + lo;
              if (kcol > qrow) sc[rf][ct][rr] = -1e30f;
            }
      }

      // ---- online softmax (exp2 domain; row reduce over lane bits 0..3)
#pragma unroll
      for (int rf = 0; rf < 2; ++rf) {
#pragma unroll
        for (int rr = 0; rr < 4; ++rr) {
          float tm = fmaxf(fmaxf(sc[rf][0][rr], sc[rf][1][rr]),
                           fmaxf(sc[rf][2][rr], sc[rf][3][rr]));
          tm = fmaxf(tm, __shfl_xor(tm, 1));
          tm = fmaxf(tm, __shfl_xor(tm, 2));
          tm = fmaxf(tm, __shfl_xor(tm, 4));
          tm = fmaxf(tm, __shfl_xor(tm, 8));
          float mn = fmaxf(m_s[rf][rr], tm);
          float corr = exp2f(m_s[rf][rr] - mn);
          m_s[rf][rr] = mn;
          float rs = 0.f;
#pragma unroll
          for (int ct = 0; ct < 4; ++ct) {
            float e = exp2f(sc[rf][ct][rr] - mn);
            sc[rf][ct][rr] = e;
            rs += e;
          }
          rs += __shfl_xor(rs, 1);
          rs += __shfl_xor(rs, 2);
          rs += __shfl_xor(rs, 4);
          rs += __shfl_xor(rs, 8);
          l_s[rf][rr] = l_s[rf][rr] * corr + rs;
#pragma unroll
          for (int dt = 0; dt < 4; ++dt) o_acc[rf][dt][rr] *= corr;
        }
      }

      // ---- P -> per-wave LDS (XOR-swizzled) -> A-frags
      char* pw = (char*)&Ps[wave][0];
#pragma unroll
      for (int rf = 0; rf < 2; ++rf)
#pragma unroll
        for (int ct = 0; ct < 4; ++ct)
#pragma unroll
          for (int rr = 0; rr < 4; ++rr) {
            int row = rf * 16 + hi * 4 + rr;
            *(unsigned short*)(pw + row * 128 + ((2 * (ct * 16 + lo)) ^ ((row & 7) << 4))) =
                f2bf(sc[rf][ct][rr]);
          }
      bf16x8 ap[2][2];
#pragma unroll
      for (int rf = 0; rf < 2; ++rf)
#pragma unroll
        for (int kk = 0; kk < 2; ++kk) {
          int rowA = rf * 16 + lo;
          ap[rf][kk] = *reinterpret_cast<const bf16x8*>(
              pw + rowA * 128 + ((kk * 64 + hi * 16) ^ ((rowA & 7) << 4)));
        }

      // ---- PV
      bf16x8 bv[4][2];
#pragma unroll
      for (int dt = 0; dt < 4; ++dt)
#pragma unroll
        for (int kk = 0; kk < 2; ++kk) {
          int row = dt * 16 + lo;
          bv[dt][kk] = *reinterpret_cast<const bf16x8*>(
              (const char*)&Vs[cur][0] + row * 128 + ((kk * 64 + hi * 16) ^ ((row & 7) << 4)));
        }
      __builtin_amdgcn_s_setprio(1);
#pragma unroll
      for (int rf = 0; rf < 2; ++rf)
#pragma unroll
        for (int dt = 0; dt < 4; ++dt) {
          o_acc[rf][dt] = __builtin_amdgcn_mfma_f32_16x16x32_bf16(ap[rf][0], bv[dt][0], o_acc[rf][dt], 0, 0, 0);
          o_acc[rf][dt] = __builtin_amdgcn_mfma_f32_16x16x32_bf16(ap[rf][1], bv[dt][1], o_acc[rf][dt], 0, 0, 0);
        }
      __builtin_amdgcn_s_setprio(0);
    }

    __builtin_amdgcn_s_barrier();
    __builtin_amdgcn_sched_barrier(0);
  }

  // ---- epilogue
#pragma unroll
  for (int rf = 0; rf < 2; ++rf) {
    float inv_l[4];
#pragma unroll
    for (int rr = 0; rr < 4; ++rr) inv_l[rr] = 1.f / l_s[rf][rr];
#pragma unroll
    for (int dt = 0; dt < 4; ++dt)
#pragma unroll
      for (int rr = 0; rr < 4; ++rr) {
        int srow = qrow0 + rf * 16 + hi * 4 + rr;
        int d    = dt * 16 + lo;
        ob[(size_t)(b * S_ + srow) * H_ + h * HD_ + d] = f2bf(o_acc[rf][dt][rr] * inv_l[rr]);
      }
  }
}

// ---------------------------------------------------------------- launch
extern "C" void kernel_launch(void* const* d_in, const int* in_sizes, int n_in,
                              void* d_out, int out_size, void* d_ws, size_t ws_size,
                              hipStream_t stream) {
  (void)in_sizes; (void)n_in; (void)out_size; (void)ws_size;
  const float* hs   = (const float*)d_in[0];
  const float* qkvw = (const float*)d_in[1];
  const float* ow   = (const float*)d_in[2];
  const int*   pos  = (const int*)d_in[3];

  char* ws = (char*)d_ws;
  unsigned short* Xb = (unsigned short*)(ws);                        // 16 MB (reused as attn out)
  unsigned short* Wq = (unsigned short*)(ws + (16ull << 20));        // 24 MB
  unsigned short* Ob = (unsigned short*)(ws + (40ull << 20));        //  8 MB
  unsigned short* Qb = (unsigned short*)(ws + (48ull << 20));        // 16 MB
  unsigned short* Kb = (unsigned short*)(ws + (64ull << 20));        // 16 MB
  unsigned short* Vt = (unsigned short*)(ws + (80ull << 20));        // 16 MB

  cast_kernel<<<2048, 256, 0, stream>>>(hs,   Xb, (B_ * S_ * H_) / 4);
  cast_kernel<<<2048, 256, 0, stream>>>(qkvw, Wq, (3 * H_ * H_) / 4);
  cast_kernel<<<2048, 256, 0, stream>>>(ow,   Ob, (H_ * H_) / 4);

  gemm_bt<0><<<dim3(32, 48), 256, 0, stream>>>(Xb, Wq, nullptr, Qb, Kb, Vt,
                                               B_ * S_, 3 * H_, H_);
  rope_kernel<<<(B_ * NH_ * S_) / 256, 256, 0, stream>>>(Qb, Kb, pos);
  attn_fwd<<<dim3(S_ / 256, B_ * NH_), 512, 0, stream>>>(Qb, Kb, Vt, Xb);
  gemm_bt<1><<<dim3(32, 16), 256, 0, stream>>>(Xb, Ob, (float*)d_out,
                                               nullptr, nullptr, nullptr,
                                               B_ * S_, H_, H_);
}

// Round 5
// 499.717 us; speedup vs baseline: 1.1950x; 1.1950x over previous
//
#include <hip/hip_runtime.h>
#include <hip/hip_bf16.h>
#include <math.h>

#define B_   2
#define S_   2048
#define H_   2048
#define NH_  32
#define HD_  64

typedef __bf16 bf16_t;
typedef bf16_t bf16x8 __attribute__((ext_vector_type(8)));
typedef float  f32x4  __attribute__((ext_vector_type(4)));

__device__ __forceinline__ float bf2f(unsigned short u) {
  unsigned int x = ((unsigned int)u) << 16;
  return __builtin_bit_cast(float, x);
}
__device__ __forceinline__ unsigned short f2bf(float f) {
  unsigned int u = __builtin_bit_cast(unsigned int, f);
  u += 0x7FFFu + ((u >> 16) & 1u);
  return (unsigned short)(u >> 16);
}

__device__ __forceinline__ void gload16(const void* g, void* l) {
  __builtin_amdgcn_global_load_lds((const __attribute__((address_space(1))) void*)g,
                                   (__attribute__((address_space(3))) void*)l, 16, 0, 0);
}

// ---------------------------------------------------------------- cast fp32 -> bf16
__global__ void cast_kernel(const float* __restrict__ in, unsigned short* __restrict__ out, int n4) {
  int stride = gridDim.x * blockDim.x;
  for (int i = blockIdx.x * blockDim.x + threadIdx.x; i < n4; i += stride) {
    float4 v = reinterpret_cast<const float4*>(in)[i];
    ushort4 o;
    o.x = f2bf(v.x); o.y = f2bf(v.y); o.z = f2bf(v.z); o.w = f2bf(v.w);
    reinterpret_cast<ushort4*>(out)[i] = o;
  }
}

// ---------------------------------------------------------------- GEMM (A[M][K] x Bt[N][K])
template<int EPI>
__global__ __launch_bounds__(256) void gemm_bt(
    const unsigned short* __restrict__ A, const unsigned short* __restrict__ Bt,
    float* __restrict__ outF,
    unsigned short* __restrict__ qb, unsigned short* __restrict__ kb, unsigned short* __restrict__ vt,
    int M, int N, int K)
{
  __shared__ unsigned short As[128 * 64];
  __shared__ unsigned short Bs[128 * 64];
  const int tid  = threadIdx.x;
  const int lane = tid & 63;
  const int wave = tid >> 6;
  const int lo = lane & 15, hi = lane >> 4;
  const int wr = wave >> 1, wc = wave & 1;
  const int m0 = blockIdx.x * 128;
  const int n0 = blockIdx.y * 128;

  const unsigned short* asrc[4];
  const unsigned short* bsrc[4];
  unsigned short* adst[4];
  unsigned short* bdst[4];
#pragma unroll
  for (int i = 0; i < 4; ++i) {
    int idx = i * 256 + tid;
    int r  = idx >> 3;
    int cb = (idx & 7) * 16;
    int cs = cb ^ ((r & 7) << 4);
    asrc[i] = A  + (size_t)(m0 + r) * K + (cs >> 1);
    bsrc[i] = Bt + (size_t)(n0 + r) * K + (cs >> 1);
    adst[i] = &As[idx * 8];
    bdst[i] = &Bs[idx * 8];
  }

  f32x4 zero = {0.f, 0.f, 0.f, 0.f};
  f32x4 acc[4][4];
#pragma unroll
  for (int i = 0; i < 4; ++i)
#pragma unroll
    for (int j = 0; j < 4; ++j) acc[i][j] = zero;

  for (int k0 = 0; k0 < K; k0 += 64) {
    __syncthreads();
#pragma unroll
    for (int i = 0; i < 4; ++i) gload16(asrc[i] + k0, adst[i]);
#pragma unroll
    for (int i = 0; i < 4; ++i) gload16(bsrc[i] + k0, bdst[i]);
    __syncthreads();
#pragma unroll
    for (int kk = 0; kk < 2; ++kk) {
      bf16x8 af[4], bfm[4];
#pragma unroll
      for (int i = 0; i < 4; ++i) {
        int ra = wr * 64 + i * 16 + lo;
        af[i] = *reinterpret_cast<const bf16x8*>(
            (const char*)As + ra * 128 + ((kk * 64 + hi * 16) ^ ((ra & 7) << 4)));
        int rb = wc * 64 + i * 16 + lo;
        bfm[i] = *reinterpret_cast<const bf16x8*>(
            (const char*)Bs + rb * 128 + ((kk * 64 + hi * 16) ^ ((rb & 7) << 4)));
      }
#pragma unroll
      for (int i = 0; i < 4; ++i)
#pragma unroll
        for (int j = 0; j < 4; ++j)
          acc[i][j] = __builtin_amdgcn_mfma_f32_16x16x32_bf16(af[i], bfm[j], acc[i][j], 0, 0, 0);
    }
  }

#pragma unroll
  for (int i = 0; i < 4; ++i) {
#pragma unroll
    for (int j = 0; j < 4; ++j) {
#pragma unroll
      for (int r = 0; r < 4; ++r) {
        int row = m0 + wr * 64 + i * 16 + hi * 4 + r;
        int col = n0 + wc * 64 + j * 16 + lo;
        float v = acc[i][j][r];
        if (EPI == 0) {
          int sec = col >> 11;
          int hh  = (col >> 6) & 31;
          int d   = col & 63;
          int b   = row >> 11;
          int s   = row & 2047;
          unsigned short bv = f2bf(v);
          if (sec == 0)      qb[((size_t)(b * NH_ + hh) * S_ + s) * HD_ + d] = bv;
          else if (sec == 1) kb[((size_t)(b * NH_ + hh) * S_ + s) * HD_ + d] = bv;
          else               vt[((size_t)(b * NH_ + hh) * HD_ + d) * S_ + s] = bv;
        } else {
          outF[(size_t)row * N + col] = v;
        }
      }
    }
  }
}

// ---------------------------------------------------------------- RoPE (in-place on bf16 Q/K)
__global__ void rope_kernel(unsigned short* __restrict__ qb, unsigned short* __restrict__ kb,
                            const int* __restrict__ pos) {
  int idx = blockIdx.x * blockDim.x + threadIdx.x;
  if (idx >= B_ * NH_ * S_) return;
  int s  = idx & (S_ - 1);
  int bh = idx >> 11;
  int b  = bh >> 5;
  float p = (float)pos[b * S_ + s];
  const float invf[8] = {1.0f, 0.31622776601683794f, 0.1f, 0.031622776601683791f,
                         0.01f, 0.0031622776601683794f, 0.001f, 0.00031622776601683794f};
  unsigned short* q = qb + (size_t)idx * HD_;
  unsigned short* k = kb + (size_t)idx * HD_;
#pragma unroll
  for (int i = 0; i < 8; ++i) {
    float ang = p * invf[i];
    float sn, c;
    sincosf(ang, &sn, &c);
    float q1 = bf2f(q[i]), q2 = bf2f(q[i + 8]);
    q[i]     = f2bf(q1 * c - q2 * sn);
    q[i + 8] = f2bf(q2 * c + q1 * sn);
    float k1 = bf2f(k[i]), k2 = bf2f(k[i + 8]);
    k[i]     = f2bf(k1 * c - k2 * sn);
    k[i + 8] = f2bf(k2 * c + k1 * sn);
  }
}

// ---------------------------------------------------------------- causal flash attention
// 4 waves/block; each block owns TWO 128-row q-tiles, mirror-paired (j, 15-j) for one
// head -> uniform work per block (34 compute-iters), K/V fetch + LDS reads shared by
// both tiles, per-wave 2-stream ILP. K/V double-buffered via global_load_lds
// (pre-swizzled source, XOR bank swizzle), counted vmcnt(4). exp2-domain softmax.
__global__ __launch_bounds__(256, 2) void attn_fwd(
    const unsigned short* __restrict__ qb, const unsigned short* __restrict__ kb,
    const unsigned short* __restrict__ vt, unsigned short* __restrict__ ob)
{
  __shared__ unsigned short Ks[2][64 * 64];
  __shared__ unsigned short Vs[2][64 * 64];
  __shared__ unsigned short Ps[4][2][32 * 64];
  const int bid  = blockIdx.x;
  const int j    = bid >> 6;          // 0..7
  const int bh   = bid & 63;
  const int tid  = threadIdx.x;
  const int lane = tid & 63;
  const int wave = tid >> 6;
  const int lo = lane & 15, hi = lane >> 4;
  const int b = bh >> 5, h = bh & 31;
  const unsigned short* Qg = qb + (size_t)bh * S_ * HD_;
  const unsigned short* Kg = kb + (size_t)bh * S_ * HD_;
  const unsigned short* Vg = vt + (size_t)bh * HD_ * S_;

  const int qt[2]    = {j, 15 - j};
  const int qrow0[2] = {j * 128 + wave * 32, (15 - j) * 128 + wave * 32};

  // Q fragments for both tiles, pre-scaled by (1/8)*log2(e) (exp2-domain scores)
  const float qscale = 0.125f * 1.4426950408889634f;
  bf16x8 aq[2][2][2];
#pragma unroll
  for (int t = 0; t < 2; ++t)
#pragma unroll
    for (int rf = 0; rf < 2; ++rf)
#pragma unroll
      for (int kk = 0; kk < 2; ++kk) {
        bf16x8 tt = *reinterpret_cast<const bf16x8*>(
            Qg + (size_t)(qrow0[t] + rf * 16 + lo) * HD_ + kk * 32 + hi * 8);
#pragma unroll
        for (int e = 0; e < 8; ++e) aq[t][rf][kk][e] = (bf16_t)((float)tt[e] * qscale);
      }

  f32x4 zero = {0.f, 0.f, 0.f, 0.f};
  float m_s[2][2][4], l_s[2][2][4];
  f32x4 o_acc[2][2][4];
#pragma unroll
  for (int t = 0; t < 2; ++t)
#pragma unroll
    for (int rf = 0; rf < 2; ++rf)
#pragma unroll
      for (int r = 0; r < 4; ++r) {
        m_s[t][rf][r] = -1e30f; l_s[t][rf][r] = 0.f;
        o_acc[t][rf][r] = zero;
      }

  auto stage = [&](int kt, int buf) {
#pragma unroll
    for (int i = 0; i < 2; ++i) {
      int idx = i * 256 + tid;
      int r   = idx >> 3;
      int cs  = ((idx & 7) * 16) ^ ((r & 7) << 4);
      gload16(Kg + (size_t)(kt * 64 + r) * HD_ + (cs >> 1), &Ks[buf][idx * 8]);
      gload16(Vg + (size_t)r * S_ + kt * 64 + (cs >> 1), &Vs[buf][idx * 8]);
    }
  };

  const int nkt = 2 * (15 - j) + 2;
  stage(0, 0);

  for (int kt = 0; kt < nkt; ++kt) {
    const int cur = kt & 1;
    if (kt + 1 < nkt) {
      stage(kt + 1, cur ^ 1);
      asm volatile("s_waitcnt vmcnt(4)" ::: "memory");
    } else {
      asm volatile("s_waitcnt vmcnt(0)" ::: "memory");
    }
    __builtin_amdgcn_s_barrier();
    __builtin_amdgcn_sched_barrier(0);

    // ---- K fragments (shared by both q-tiles)
    bf16x8 bk[4][2];
#pragma unroll
    for (int ct = 0; ct < 4; ++ct)
#pragma unroll
      for (int kk = 0; kk < 2; ++kk) {
        int row = ct * 16 + lo;
        bk[ct][kk] = *reinterpret_cast<const bf16x8*>(
            (const char*)&Ks[cur][0] + row * 128 + ((kk * 64 + hi * 16) ^ ((row & 7) << 4)));
      }

    // ---- per-tile: QK^T, online softmax, P -> LDS
#pragma unroll
    for (int t = 0; t < 2; ++t) {
      if (kt * 64 <= qrow0[t] + 31) {
        f32x4 sc[2][4];
        __builtin_amdgcn_s_setprio(1);
#pragma unroll
        for (int rf = 0; rf < 2; ++rf)
#pragma unroll
          for (int ct = 0; ct < 4; ++ct) {
            f32x4 a = zero;
            a = __builtin_amdgcn_mfma_f32_16x16x32_bf16(aq[t][rf][0], bk[ct][0], a, 0, 0, 0);
            a = __builtin_amdgcn_mfma_f32_16x16x32_bf16(aq[t][rf][1], bk[ct][1], a, 0, 0, 0);
            sc[rf][ct] = a;
          }
        __builtin_amdgcn_s_setprio(0);

        if (kt * 64 + 63 > qrow0[t]) {  // diagonal tile: causal mask
#pragma unroll
          for (int rf = 0; rf < 2; ++rf)
#pragma unroll
            for (int ct = 0; ct < 4; ++ct)
#pragma unroll
              for (int rr = 0; rr < 4; ++rr) {
                int qrow = qrow0[t] + rf * 16 + hi * 4 + rr;
                int kcol = kt * 64 + ct * 16 + lo;
                if (kcol > qrow) sc[rf][ct][rr] = -1e30f;
              }
        }

#pragma unroll
        for (int rf = 0; rf < 2; ++rf) {
#pragma unroll
          for (int rr = 0; rr < 4; ++rr) {
            float tm = fmaxf(fmaxf(sc[rf][0][rr], sc[rf][1][rr]),
                             fmaxf(sc[rf][2][rr], sc[rf][3][rr]));
            tm = fmaxf(tm, __shfl_xor(tm, 1));
            tm = fmaxf(tm, __shfl_xor(tm, 2));
            tm = fmaxf(tm, __shfl_xor(tm, 4));
            tm = fmaxf(tm, __shfl_xor(tm, 8));
            float mn = fmaxf(m_s[t][rf][rr], tm);
            float corr = exp2f(m_s[t][rf][rr] - mn);
            m_s[t][rf][rr] = mn;
            float rs = 0.f;
#pragma unroll
            for (int ct = 0; ct < 4; ++ct) {
              float e = exp2f(sc[rf][ct][rr] - mn);
              sc[rf][ct][rr] = e;
              rs += e;
            }
            rs += __shfl_xor(rs, 1);
            rs += __shfl_xor(rs, 2);
            rs += __shfl_xor(rs, 4);
            rs += __shfl_xor(rs, 8);
            l_s[t][rf][rr] = l_s[t][rf][rr] * corr + rs;
#pragma unroll
            for (int dt = 0; dt < 4; ++dt) o_acc[t][rf][dt][rr] *= corr;
          }
        }

        char* pw = (char*)&Ps[wave][t][0];
#pragma unroll
        for (int rf = 0; rf < 2; ++rf)
#pragma unroll
          for (int ct = 0; ct < 4; ++ct)
#pragma unroll
            for (int rr = 0; rr < 4; ++rr) {
              int row = rf * 16 + hi * 4 + rr;
              *(unsigned short*)(pw + row * 128 + ((2 * (ct * 16 + lo)) ^ ((row & 7) << 4))) =
                  f2bf(sc[rf][ct][rr]);
            }
      }
    }

    // ---- V fragments (shared) + per-tile PV
    bf16x8 bv[4][2];
#pragma unroll
    for (int dt = 0; dt < 4; ++dt)
#pragma unroll
      for (int kk = 0; kk < 2; ++kk) {
        int row = dt * 16 + lo;
        bv[dt][kk] = *reinterpret_cast<const bf16x8*>(
            (const char*)&Vs[cur][0] + row * 128 + ((kk * 64 + hi * 16) ^ ((row & 7) << 4)));
      }
#pragma unroll
    for (int t = 0; t < 2; ++t) {
      if (kt * 64 <= qrow0[t] + 31) {
        char* pw = (char*)&Ps[wave][t][0];
        bf16x8 ap[2][2];
#pragma unroll
        for (int rf = 0; rf < 2; ++rf)
#pragma unroll
          for (int kk = 0; kk < 2; ++kk) {
            int rowA = rf * 16 + lo;
            ap[rf][kk] = *reinterpret_cast<const bf16x8*>(
                pw + rowA * 128 + ((kk * 64 + hi * 16) ^ ((rowA & 7) << 4)));
          }
        __builtin_amdgcn_s_setprio(1);
#pragma unroll
        for (int rf = 0; rf < 2; ++rf)
#pragma unroll
          for (int dt = 0; dt < 4; ++dt) {
            o_acc[t][rf][dt] = __builtin_amdgcn_mfma_f32_16x16x32_bf16(ap[rf][0], bv[dt][0], o_acc[t][rf][dt], 0, 0, 0);
            o_acc[t][rf][dt] = __builtin_amdgcn_mfma_f32_16x16x32_bf16(ap[rf][1], bv[dt][1], o_acc[t][rf][dt], 0, 0, 0);
          }
        __builtin_amdgcn_s_setprio(0);
      }
    }

    __builtin_amdgcn_s_barrier();
    __builtin_amdgcn_sched_barrier(0);
  }

  // ---- epilogue (both tiles)
#pragma unroll
  for (int t = 0; t < 2; ++t)
#pragma unroll
    for (int rf = 0; rf < 2; ++rf) {
      float inv_l[4];
#pragma unroll
      for (int rr = 0; rr < 4; ++rr) inv_l[rr] = 1.f / l_s[t][rf][rr];
#pragma unroll
      for (int dt = 0; dt < 4; ++dt)
#pragma unroll
        for (int rr = 0; rr < 4; ++rr) {
          int srow = qrow0[t] + rf * 16 + hi * 4 + rr;
          int d    = dt * 16 + lo;
          ob[(size_t)(b * S_ + srow) * H_ + h * HD_ + d] = f2bf(o_acc[t][rf][dt][rr] * inv_l[rr]);
        }
    }
}

// ---------------------------------------------------------------- launch
extern "C" void kernel_launch(void* const* d_in, const int* in_sizes, int n_in,
                              void* d_out, int out_size, void* d_ws, size_t ws_size,
                              hipStream_t stream) {
  (void)in_sizes; (void)n_in; (void)out_size; (void)ws_size;
  const float* hs   = (const float*)d_in[0];
  const float* qkvw = (const float*)d_in[1];
  const float* ow   = (const float*)d_in[2];
  const int*   pos  = (const int*)d_in[3];

  char* ws = (char*)d_ws;
  unsigned short* Xb = (unsigned short*)(ws);                        // 16 MB (reused as attn out)
  unsigned short* Wq = (unsigned short*)(ws + (16ull << 20));        // 24 MB
  unsigned short* Ob = (unsigned short*)(ws + (40ull << 20));        //  8 MB
  unsigned short* Qb = (unsigned short*)(ws + (48ull << 20));        // 16 MB
  unsigned short* Kb = (unsigned short*)(ws + (64ull << 20));        // 16 MB
  unsigned short* Vt = (unsigned short*)(ws + (80ull << 20));        // 16 MB

  cast_kernel<<<2048, 256, 0, stream>>>(hs,   Xb, (B_ * S_ * H_) / 4);
  cast_kernel<<<2048, 256, 0, stream>>>(qkvw, Wq, (3 * H_ * H_) / 4);
  cast_kernel<<<2048, 256, 0, stream>>>(ow,   Ob, (H_ * H_) / 4);

  gemm_bt<0><<<dim3(32, 48), 256, 0, stream>>>(Xb, Wq, nullptr, Qb, Kb, Vt,
                                               B_ * S_, 3 * H_, H_);
  rope_kernel<<<(B_ * NH_ * S_) / 256, 256, 0, stream>>>(Qb, Kb, pos);
  attn_fwd<<<512, 256, 0, stream>>>(Qb, Kb, Vt, Xb);
  gemm_bt<1><<<dim3(32, 16), 256, 0, stream>>>(Xb, Ob, (float*)d_out,
                                               nullptr, nullptr, nullptr,
                                               B_ * S_, H_, H_);
}